// Round 8
// baseline (267.094 us; speedup 1.0000x reference)
//
#include <hip/hip_runtime.h>
#include <hip/hip_bf16.h>

#define NROWS 16384
#define DIM   256
#define SEGS  8
#define BN    128                     // staged tile: 128 cols x 256 k (fp8) = 32 KB
#define NT    ((NROWS / SEGS) / BN)   // 16 tiles per segment
#define NBLK  (SEGS * (NROWS / 256)) // 512 sim blocks
#define INVT  14.285714285714286f
#define C1f   20.60992915555662f      // log2(e)/0.07 ; A is pre-scaled by this
#define LN2f  0.6931471805599453f

typedef __attribute__((ext_vector_type(8)))  int   int8v;    // fp8 A/B fragment (32 bytes)
typedef __attribute__((ext_vector_type(16))) float f32x16;   // 32x32 MFMA accumulator

#define SCALE1 0x7F7F7F7F   // E8M0 = 1.0 in every byte (opsel-proof)

// Kernel 1: L2-normalize (fp32); emit fp8 e4m3 A (row-major, xC1) and fp8 B in the
// DMA staging/swizzle layout, plus exact fp32 diagonal. Also zeroes the done-counter.
// B layout (16B chunks): chunk(col,kcb) = (col>>7)*2048 + ((col>>6)&1)*1024
//                                        + kcb*64 + ((col&63) ^ (kcb&7))
__global__ __launch_bounds__(256) void norm_diag_kernel(
    const float* __restrict__ fl, const float* __restrict__ fg,
    unsigned char* __restrict__ A, unsigned char* __restrict__ B,
    float* __restrict__ diag, unsigned* __restrict__ cnt)
{
    int tid  = threadIdx.x;
    int wave = tid >> 6, lane = tid & 63;
    int row  = blockIdx.x * 4 + wave;
    if (blockIdx.x == 0 && tid == 0) cnt[0] = 0;   // reset last-block counter

    float4 xl = ((const float4*)(fl + (size_t)row * DIM))[lane];
    float4 xg = ((const float4*)(fg + (size_t)row * DIM))[lane];
    float ssl = xl.x*xl.x + xl.y*xl.y + xl.z*xl.z + xl.w*xl.w;
    float ssg = xg.x*xg.x + xg.y*xg.y + xg.z*xg.z + xg.w*xg.w;
    for (int m = 1; m < 64; m <<= 1) {
        ssl += __shfl_xor(ssl, m, 64);
        ssg += __shfl_xor(ssg, m, 64);
    }
    float il = 1.0f / fmaxf(sqrtf(ssl), 1e-12f);
    float ig = 1.0f / fmaxf(sqrtf(ssg), 1e-12f);
    float nl0 = xl.x*il, nl1 = xl.y*il, nl2 = xl.z*il, nl3 = xl.w*il;
    float ng0 = xg.x*ig, ng1 = xg.y*ig, ng2 = xg.z*ig, ng3 = xg.w*ig;

    int pa = __builtin_amdgcn_cvt_pk_fp8_f32(nl0 * C1f, nl1 * C1f, 0, false);
    pa     = __builtin_amdgcn_cvt_pk_fp8_f32(nl2 * C1f, nl3 * C1f, pa, true);
    int pb = __builtin_amdgcn_cvt_pk_fp8_f32(ng0, ng1, 0, false);
    pb     = __builtin_amdgcn_cvt_pk_fp8_f32(ng2, ng3, pb, true);
    ((int*)(A + (size_t)row * DIM))[lane] = pa;   // A row-major

    {   // B swizzled to the staging layout (verified R6)
        int kcb = lane >> 2;
        int b4  = lane & 3;
        int c64 = row & 63;
        unsigned chunk = (unsigned)((row >> 7) * 2048 + ((row >> 6) & 1) * 1024
                                    + kcb * 64 + (c64 ^ (kcb & 7)));
        ((int*)B)[chunk * 4 + b4] = pb;
    }

    float d = nl0*ng0 + nl1*ng1 + nl2*ng2 + nl3*ng3;   // exact fp32 diagonal
    for (int m = 1; m < 64; m <<= 1) d += __shfl_xor(d, m, 64);
    if (lane == 0) diag[row] = d;
}

// Kernel 2: fused sim-GEMM + fixed-max sumexp + (last block) final reduce.
// MX-fp8 32x32x64, DMA prefetch across single barrier (R6 structure, 72.6 us proven).
// NEW: ping-pong accumulators accP[2] -> exp2 epilogue of half-tile h-1 is issued
// while the MFMA chain of half-tile h runs (independent registers; scheduler
// interleaves VALU into MFMA stall cycles).
__global__ __launch_bounds__(256, 2) void sim_lse_kernel(
    const unsigned char* __restrict__ A, const unsigned char* __restrict__ B,
    float* __restrict__ lpart, const float* __restrict__ diag,
    unsigned* __restrict__ cnt, float* __restrict__ out)
{
    __shared__ __align__(16) unsigned char bt[2 * BN * DIM];   // 2 x 32 KB double buffer

    int tid  = threadIdx.x;
    int lane = tid & 63;
    int l31  = lane & 31, half = lane >> 5;
    int wave = tid >> 6;
    int seg  = blockIdx.x;
    int rowBase = blockIdx.y * 256 + wave * 64;

    // Preload A fragments: lane(l31,half) holds A[m=l31][k = kk*64 + half*32 + 0..31]
    int8v af[2][4];
#pragma unroll
    for (int s = 0; s < 2; ++s) {
        const unsigned char* ap = A + (size_t)(rowBase + s*32 + l31) * DIM + half * 32;
#pragma unroll
        for (int kk = 0; kk < 4; ++kk) {
            int4 lo = *(const int4*)(ap + kk * 64);
            int4 hi = *(const int4*)(ap + kk * 64 + 16);
            int8v v;
            v[0]=lo.x; v[1]=lo.y; v[2]=lo.z; v[3]=lo.w;
            v[4]=hi.x; v[5]=hi.y; v[6]=hi.z; v[7]=hi.w;
            af[s][kk] = v;
        }
    }

    f32x16 lv[2];
    f32x16 Z;
#pragma unroll
    for (int r = 0; r < 16; ++r) { lv[0][r] = 0.0f; lv[1][r] = 0.0f; Z[r] = 0.0f; }

    int T0 = seg * NT;

    auto stage = [&](int T, unsigned bufo) {
        const unsigned char* g = B + (size_t)T * (BN * DIM) + (wave * 512 + lane) * 16;
        unsigned lo = bufo + (unsigned)(wave * 512) * 16;
#pragma unroll
        for (int j = 0; j < 8; ++j) {
            __builtin_amdgcn_global_load_lds(
                (const __attribute__((address_space(1))) unsigned int*)(g + j * 1024),
                (__attribute__((address_space(3))) unsigned int*)&bt[lo + j * 1024],
                16, 0, 0);
        }
    };

    auto epi = [&](f32x16 (&ac)[2][2]) {
#pragma unroll
        for (int s = 0; s < 2; ++s) {
            f32x16 e;
#pragma unroll
            for (int r = 0; r < 16; ++r)
                e[r] = __builtin_amdgcn_exp2f(ac[s][0][r]) + __builtin_amdgcn_exp2f(ac[s][1][r]);
            lv[s] += e;
        }
    };

    stage(T0, 0);

    f32x16 accP[2][2][2];   // [parity p][row-set s][col-set c]

    for (int t = 0; t < NT; ++t) {
        unsigned bufo = (t & 1) ? (unsigned)(BN * DIM) : 0u;
        __syncthreads();   // drains own tile-t DMA (in flight a full tile), syncs waves

        if (t + 1 < NT)
            stage(T0 + t + 1, (t & 1) ? 0u : (unsigned)(BN * DIM));

#pragma unroll
        for (int p = 0; p < 2; ++p) {
            unsigned subo = bufo + (unsigned)p * 16384;
            f32x16 (&acc)[2][2] = accP[p];
#pragma unroll
            for (int kk = 0; kk < 4; ++kk) {
                int8v bfr[2];
#pragma unroll
                for (int c = 0; c < 2; ++c) {
                    int col = c * 32 + l31;
                    int kcb = kk * 4 + half * 2;
                    unsigned p0 = (unsigned)(kcb * 64 + (col ^ (kcb & 7)));
                    unsigned p1 = (unsigned)((kcb + 1) * 64 + (col ^ ((kcb + 1) & 7)));
                    int4 lo = *(const int4*)&bt[subo + p0 * 16];
                    int4 hi = *(const int4*)&bt[subo + p1 * 16];
                    int8v v;
                    v[0]=lo.x; v[1]=lo.y; v[2]=lo.z; v[3]=lo.w;
                    v[4]=hi.x; v[5]=hi.y; v[6]=hi.z; v[7]=hi.w;
                    bfr[c] = v;
                }
#pragma unroll
                for (int c = 0; c < 2; ++c) {
                    if (kk == 0) {
                        acc[0][c] = __builtin_amdgcn_mfma_scale_f32_32x32x64_f8f6f4(
                            af[0][0], bfr[c], Z, 0, 0, 0, SCALE1, 0, SCALE1);
                        acc[1][c] = __builtin_amdgcn_mfma_scale_f32_32x32x64_f8f6f4(
                            af[1][0], bfr[c], Z, 0, 0, 0, SCALE1, 0, SCALE1);
                    } else {
                        acc[0][c] = __builtin_amdgcn_mfma_scale_f32_32x32x64_f8f6f4(
                            af[0][kk], bfr[c], acc[0][c], 0, 0, 0, SCALE1, 0, SCALE1);
                        acc[1][c] = __builtin_amdgcn_mfma_scale_f32_32x32x64_f8f6f4(
                            af[1][kk], bfr[c], acc[1][c], 0, 0, 0, SCALE1, 0, SCALE1);
                    }
                }
            }
            // Deferred epilogue of the PREVIOUS half-tile: independent of the MFMA
            // chain above -> scheduler interleaves these exp2 into MFMA stalls.
            if (p == 0) { if (t > 0) epi(accP[1]); }
            else         epi(accP[0]);
        }
    }
    epi(accP[1]);   // last half-tile

    // Sum across the 32 column-lanes
#pragma unroll
    for (int s = 0; s < 2; ++s)
#pragma unroll
        for (int r = 0; r < 16; ++r) {
            float v = lv[s][r];
            v += __shfl_xor(v, 1, 64);
            v += __shfl_xor(v, 2, 64);
            v += __shfl_xor(v, 4, 64);
            v += __shfl_xor(v, 8, 64);
            v += __shfl_xor(v, 16, 64);
            lv[s][r] = v;
        }
    if (l31 == 0) {
#pragma unroll
        for (int s = 0; s < 2; ++s)
#pragma unroll
            for (int r = 0; r < 16; ++r) {
                int row = rowBase + s*32 + (r & 3) + 8*(r >> 2) + 4*half;
                lpart[(size_t)seg * NROWS + row] = lv[s][r];
            }
    }

    // ---- last-block final reduce (replaces kernel 3) ----
    __threadfence();                       // release lpart stores (device scope)
    __shared__ unsigned lastdone;
    if (tid == 0) lastdone = (atomicAdd(cnt, 1u) == (unsigned)(NBLK - 1));
    __syncthreads();
    if (lastdone) {
        __threadfence();                   // acquire all blocks' lpart
        float s = 0.0f;
        for (int row = tid; row < NROWS; row += 256) {
            float tt = 0.0f;
#pragma unroll
            for (int g = 0; g < SEGS; ++g) tt += lpart[(size_t)g * NROWS + row];
            s += LN2f * log2f(tt) - INVT * diag[row];
        }
        for (int m = 1; m < 64; m <<= 1) s += __shfl_xor(s, m, 64);
        float* sm = (float*)bt;            // reuse LDS
        if ((tid & 63) == 0) sm[tid >> 6] = s;
        __syncthreads();
        if (tid == 0)
            out[0] = (sm[0] + sm[1] + sm[2] + sm[3]) * (1.0f / NROWS);
    }
}

extern "C" void kernel_launch(void* const* d_in, const int* in_sizes, int n_in,
                              void* d_out, int out_size, void* d_ws, size_t ws_size,
                              hipStream_t stream) {
    const float* fl = (const float*)d_in[0];
    const float* fg = (const float*)d_in[1];
    float* out = (float*)d_out;

    char* ws = (char*)d_ws;
    unsigned char* A = (unsigned char*)ws;                         // 16384*256 = 4 MB
    unsigned char* B = A + (size_t)NROWS * DIM;                    // 4 MB (swizzled)
    float* diag  = (float*)(ws + 2 * (size_t)NROWS * DIM);         // 64 KB
    float* lpart = diag + NROWS;                                   // SEGS*N*4 = 512 KB
    unsigned* cnt = (unsigned*)(lpart + (size_t)SEGS * NROWS);     // 4 B

    norm_diag_kernel<<<NROWS / 4, 256, 0, stream>>>(fl, fg, A, B, diag, cnt);
    sim_lse_kernel<<<dim3(SEGS, NROWS / 256), 256, 0, stream>>>(A, B, lpart, diag, cnt, out);
}

// Round 9
// 193.758 us; speedup vs baseline: 1.3785x; 1.3785x over previous
//
#include <hip/hip_runtime.h>
#include <hip/hip_bf16.h>

#define NROWS 16384
#define DIM   256
#define SEGS  8
#define BN    128                     // staged tile: 128 cols x 256 k (fp8) = 32 KB
#define NT    ((NROWS / SEGS) / BN)   // 16 tiles per segment
#define NBLK  (SEGS * (NROWS / 256)) // 512 sim blocks
#define INVT  14.285714285714286f
#define C1f   20.60992915555662f      // log2(e)/0.07 ; A is pre-scaled by this
#define LN2f  0.6931471805599453f

typedef __attribute__((ext_vector_type(8)))  int   int8v;    // fp8 A/B fragment (32 bytes)
typedef __attribute__((ext_vector_type(16))) float f32x16;   // 32x32 MFMA accumulator

#define SCALE1 0x7F7F7F7F   // E8M0 = 1.0 in every byte (opsel-proof)

// Kernel 1: L2-normalize (fp32); emit fp8 e4m3 A (row-major, xC1) and fp8 B in the
// DMA staging/swizzle layout, plus exact fp32 diagonal. Also zeroes the done-counter.
// B layout (16B chunks): chunk(col,kcb) = (col>>7)*2048 + ((col>>6)&1)*1024
//                                        + kcb*64 + ((col&63) ^ (kcb&7))
__global__ __launch_bounds__(256) void norm_diag_kernel(
    const float* __restrict__ fl, const float* __restrict__ fg,
    unsigned char* __restrict__ A, unsigned char* __restrict__ B,
    float* __restrict__ diag, unsigned* __restrict__ cnt)
{
    int tid  = threadIdx.x;
    int wave = tid >> 6, lane = tid & 63;
    int row  = blockIdx.x * 4 + wave;
    if (blockIdx.x == 0 && tid == 0) cnt[0] = 0;   // reset last-block counter

    float4 xl = ((const float4*)(fl + (size_t)row * DIM))[lane];
    float4 xg = ((const float4*)(fg + (size_t)row * DIM))[lane];
    float ssl = xl.x*xl.x + xl.y*xl.y + xl.z*xl.z + xl.w*xl.w;
    float ssg = xg.x*xg.x + xg.y*xg.y + xg.z*xg.z + xg.w*xg.w;
    for (int m = 1; m < 64; m <<= 1) {
        ssl += __shfl_xor(ssl, m, 64);
        ssg += __shfl_xor(ssg, m, 64);
    }
    float il = 1.0f / fmaxf(sqrtf(ssl), 1e-12f);
    float ig = 1.0f / fmaxf(sqrtf(ssg), 1e-12f);
    float nl0 = xl.x*il, nl1 = xl.y*il, nl2 = xl.z*il, nl3 = xl.w*il;
    float ng0 = xg.x*ig, ng1 = xg.y*ig, ng2 = xg.z*ig, ng3 = xg.w*ig;

    int pa = __builtin_amdgcn_cvt_pk_fp8_f32(nl0 * C1f, nl1 * C1f, 0, false);
    pa     = __builtin_amdgcn_cvt_pk_fp8_f32(nl2 * C1f, nl3 * C1f, pa, true);
    int pb = __builtin_amdgcn_cvt_pk_fp8_f32(ng0, ng1, 0, false);
    pb     = __builtin_amdgcn_cvt_pk_fp8_f32(ng2, ng3, pb, true);
    ((int*)(A + (size_t)row * DIM))[lane] = pa;   // A row-major

    {   // B swizzled to the staging layout (verified R6)
        int kcb = lane >> 2;
        int b4  = lane & 3;
        int c64 = row & 63;
        unsigned chunk = (unsigned)((row >> 7) * 2048 + ((row >> 6) & 1) * 1024
                                    + kcb * 64 + (c64 ^ (kcb & 7)));
        ((int*)B)[chunk * 4 + b4] = pb;
    }

    float d = nl0*ng0 + nl1*ng1 + nl2*ng2 + nl3*ng3;   // exact fp32 diagonal
    for (int m = 1; m < 64; m <<= 1) d += __shfl_xor(d, m, 64);
    if (lane == 0) diag[row] = d;
}

// Kernel 2: fused sim-GEMM + fixed-max sumexp (exact R6 body, 72.6 us proven:
// single acc set, epilogue per half-tile, DMA prefetch across one barrier/tile)
// + last-block final reduce (removes kernel 3 and its full-drain boundary).
__global__ __launch_bounds__(256, 2) void sim_lse_kernel(
    const unsigned char* __restrict__ A, const unsigned char* __restrict__ B,
    float* __restrict__ lpart, const float* __restrict__ diag,
    unsigned* __restrict__ cnt, float* __restrict__ out)
{
    __shared__ __align__(16) unsigned char bt[2 * BN * DIM];   // 2 x 32 KB double buffer

    int tid  = threadIdx.x;
    int lane = tid & 63;
    int l31  = lane & 31, half = lane >> 5;
    int wave = tid >> 6;
    int seg  = blockIdx.x;
    int rowBase = blockIdx.y * 256 + wave * 64;

    // Preload A fragments: lane(l31,half) holds A[m=l31][k = kk*64 + half*32 + 0..31]
    int8v af[2][4];
#pragma unroll
    for (int s = 0; s < 2; ++s) {
        const unsigned char* ap = A + (size_t)(rowBase + s*32 + l31) * DIM + half * 32;
#pragma unroll
        for (int kk = 0; kk < 4; ++kk) {
            int4 lo = *(const int4*)(ap + kk * 64);
            int4 hi = *(const int4*)(ap + kk * 64 + 16);
            int8v v;
            v[0]=lo.x; v[1]=lo.y; v[2]=lo.z; v[3]=lo.w;
            v[4]=hi.x; v[5]=hi.y; v[6]=hi.z; v[7]=hi.w;
            af[s][kk] = v;
        }
    }

    f32x16 lv[2];
    f32x16 Z;
#pragma unroll
    for (int r = 0; r < 16; ++r) { lv[0][r] = 0.0f; lv[1][r] = 0.0f; Z[r] = 0.0f; }

    int T0 = seg * NT;

    auto stage = [&](int T, unsigned bufo) {
        const unsigned char* g = B + (size_t)T * (BN * DIM) + (wave * 512 + lane) * 16;
        unsigned lo = bufo + (unsigned)(wave * 512) * 16;
#pragma unroll
        for (int j = 0; j < 8; ++j) {
            __builtin_amdgcn_global_load_lds(
                (const __attribute__((address_space(1))) unsigned int*)(g + j * 1024),
                (__attribute__((address_space(3))) unsigned int*)&bt[lo + j * 1024],
                16, 0, 0);
        }
    };

    stage(T0, 0);

    for (int t = 0; t < NT; ++t) {
        unsigned bufo = (t & 1) ? (unsigned)(BN * DIM) : 0u;
        __syncthreads();   // drains own tile-t DMA (in flight a full tile), syncs waves

        if (t + 1 < NT)
            stage(T0 + t + 1, (t & 1) ? 0u : (unsigned)(BN * DIM));

#pragma unroll
        for (int p = 0; p < 2; ++p) {
            unsigned subo = bufo + (unsigned)p * 16384;
            f32x16 acc[2][2];
#pragma unroll
            for (int kk = 0; kk < 4; ++kk) {
                int8v bfr[2];
#pragma unroll
                for (int c = 0; c < 2; ++c) {
                    int col = c * 32 + l31;
                    int kcb = kk * 4 + half * 2;
                    unsigned p0 = (unsigned)(kcb * 64 + (col ^ (kcb & 7)));
                    unsigned p1 = (unsigned)((kcb + 1) * 64 + (col ^ ((kcb + 1) & 7)));
                    int4 lo = *(const int4*)&bt[subo + p0 * 16];
                    int4 hi = *(const int4*)&bt[subo + p1 * 16];
                    int8v v;
                    v[0]=lo.x; v[1]=lo.y; v[2]=lo.z; v[3]=lo.w;
                    v[4]=hi.x; v[5]=hi.y; v[6]=hi.z; v[7]=hi.w;
                    bfr[c] = v;
                }
#pragma unroll
                for (int c = 0; c < 2; ++c) {
                    if (kk == 0) {
                        acc[0][c] = __builtin_amdgcn_mfma_scale_f32_32x32x64_f8f6f4(
                            af[0][0], bfr[c], Z, 0, 0, 0, SCALE1, 0, SCALE1);
                        acc[1][c] = __builtin_amdgcn_mfma_scale_f32_32x32x64_f8f6f4(
                            af[1][0], bfr[c], Z, 0, 0, 0, SCALE1, 0, SCALE1);
                    } else {
                        acc[0][c] = __builtin_amdgcn_mfma_scale_f32_32x32x64_f8f6f4(
                            af[0][kk], bfr[c], acc[0][c], 0, 0, 0, SCALE1, 0, SCALE1);
                        acc[1][c] = __builtin_amdgcn_mfma_scale_f32_32x32x64_f8f6f4(
                            af[1][kk], bfr[c], acc[1][c], 0, 0, 0, SCALE1, 0, SCALE1);
                    }
                }
            }
            // Epilogue: acc = C1*dot; exp2 and accumulate
#pragma unroll
            for (int s = 0; s < 2; ++s) {
                f32x16 e;
#pragma unroll
                for (int r = 0; r < 16; ++r)
                    e[r] = __builtin_amdgcn_exp2f(acc[s][0][r]) + __builtin_amdgcn_exp2f(acc[s][1][r]);
                lv[s] += e;
            }
        }
    }

    // Sum across the 32 column-lanes
#pragma unroll
    for (int s = 0; s < 2; ++s)
#pragma unroll
        for (int r = 0; r < 16; ++r) {
            float v = lv[s][r];
            v += __shfl_xor(v, 1, 64);
            v += __shfl_xor(v, 2, 64);
            v += __shfl_xor(v, 4, 64);
            v += __shfl_xor(v, 8, 64);
            v += __shfl_xor(v, 16, 64);
            lv[s][r] = v;
        }
    if (l31 == 0) {
#pragma unroll
        for (int s = 0; s < 2; ++s)
#pragma unroll
            for (int r = 0; r < 16; ++r) {
                int row = rowBase + s*32 + (r & 3) + 8*(r >> 2) + 4*half;
                lpart[(size_t)seg * NROWS + row] = lv[s][r];
            }
    }

    // ---- last-block final reduce (replaces kernel 3) ----
    __threadfence();                       // release lpart stores (device scope)
    __shared__ unsigned lastdone;
    if (tid == 0) lastdone = (atomicAdd(cnt, 1u) == (unsigned)(NBLK - 1));
    __syncthreads();
    if (lastdone) {
        __threadfence();                   // acquire all blocks' lpart
        float s = 0.0f;
        for (int row = tid; row < NROWS; row += 256) {
            float tt = 0.0f;
#pragma unroll
            for (int g = 0; g < SEGS; ++g) tt += lpart[(size_t)g * NROWS + row];
            s += LN2f * log2f(tt) - INVT * diag[row];
        }
        for (int m = 1; m < 64; m <<= 1) s += __shfl_xor(s, m, 64);
        float* sm = (float*)bt;            // reuse LDS
        if ((tid & 63) == 0) sm[tid >> 6] = s;
        __syncthreads();
        if (tid == 0)
            out[0] = (sm[0] + sm[1] + sm[2] + sm[3]) * (1.0f / NROWS);
    }
}

extern "C" void kernel_launch(void* const* d_in, const int* in_sizes, int n_in,
                              void* d_out, int out_size, void* d_ws, size_t ws_size,
                              hipStream_t stream) {
    const float* fl = (const float*)d_in[0];
    const float* fg = (const float*)d_in[1];
    float* out = (float*)d_out;

    char* ws = (char*)d_ws;
    unsigned char* A = (unsigned char*)ws;                         // 16384*256 = 4 MB
    unsigned char* B = A + (size_t)NROWS * DIM;                    // 4 MB (swizzled)
    float* diag  = (float*)(ws + 2 * (size_t)NROWS * DIM);         // 64 KB
    float* lpart = diag + NROWS;                                   // SEGS*N*4 = 512 KB
    unsigned* cnt = (unsigned*)(lpart + (size_t)SEGS * NROWS);     // 4 B

    norm_diag_kernel<<<NROWS / 4, 256, 0, stream>>>(fl, fg, A, B, diag, cnt);
    sim_lse_kernel<<<dim3(SEGS, NROWS / 256), 256, 0, stream>>>(A, B, lpart, diag, cnt, out);
}

// Round 10
// 139.235 us; speedup vs baseline: 1.9183x; 1.3916x over previous
//
#include <hip/hip_runtime.h>
#include <hip/hip_bf16.h>

#define NROWS 16384
#define DIM   256
#define SEGS  8
#define BN    128                     // staged tile: 128 cols x 256 k (fp8) = 32 KB
#define NT    ((NROWS / SEGS) / BN)   // 16 tiles per segment
#define INVT  14.285714285714286f
#define C1f   20.60992915555662f      // log2(e)/0.07 ; A is pre-scaled by this
#define LN2f  0.6931471805599453f

typedef __attribute__((ext_vector_type(8)))  int   int8v;    // fp8 A/B fragment (32 bytes)
typedef __attribute__((ext_vector_type(16))) float f32x16;   // 32x32 MFMA accumulator

#define SCALE1 0x7F7F7F7F   // E8M0 = 1.0 in every byte (opsel-proof)

// Kernel 1: L2-normalize (fp32); emit fp8 e4m3 A (row-major, xC1) and fp8 B in the
// DMA staging/swizzle layout, plus exact fp32 diagonal. One wave per row.
// B layout (16B chunks): chunk(col,kcb) = (col>>7)*2048 + ((col>>6)&1)*1024
//                                        + kcb*64 + ((col&63) ^ (kcb&7))
__global__ __launch_bounds__(256) void norm_diag_kernel(
    const float* __restrict__ fl, const float* __restrict__ fg,
    unsigned char* __restrict__ A, unsigned char* __restrict__ B,
    float* __restrict__ diag, float* __restrict__ out)
{
    int tid  = threadIdx.x;
    int wave = tid >> 6, lane = tid & 63;
    int row  = blockIdx.x * 4 + wave;
    if (blockIdx.x == 0 && tid == 0) out[0] = 0.0f;   // zero accumulator for final atomicAdd

    float4 xl = ((const float4*)(fl + (size_t)row * DIM))[lane];
    float4 xg = ((const float4*)(fg + (size_t)row * DIM))[lane];
    float ssl = xl.x*xl.x + xl.y*xl.y + xl.z*xl.z + xl.w*xl.w;
    float ssg = xg.x*xg.x + xg.y*xg.y + xg.z*xg.z + xg.w*xg.w;
    for (int m = 1; m < 64; m <<= 1) {
        ssl += __shfl_xor(ssl, m, 64);
        ssg += __shfl_xor(ssg, m, 64);
    }
    float il = 1.0f / fmaxf(sqrtf(ssl), 1e-12f);
    float ig = 1.0f / fmaxf(sqrtf(ssg), 1e-12f);
    float nl0 = xl.x*il, nl1 = xl.y*il, nl2 = xl.z*il, nl3 = xl.w*il;
    float ng0 = xg.x*ig, ng1 = xg.y*ig, ng2 = xg.z*ig, ng3 = xg.w*ig;

    int pa = __builtin_amdgcn_cvt_pk_fp8_f32(nl0 * C1f, nl1 * C1f, 0, false);
    pa     = __builtin_amdgcn_cvt_pk_fp8_f32(nl2 * C1f, nl3 * C1f, pa, true);
    int pb = __builtin_amdgcn_cvt_pk_fp8_f32(ng0, ng1, 0, false);
    pb     = __builtin_amdgcn_cvt_pk_fp8_f32(ng2, ng3, pb, true);
    ((int*)(A + (size_t)row * DIM))[lane] = pa;   // A row-major

    {   // B swizzled to the staging layout (verified R6)
        int kcb = lane >> 2;
        int b4  = lane & 3;
        int c64 = row & 63;
        unsigned chunk = (unsigned)((row >> 7) * 2048 + ((row >> 6) & 1) * 1024
                                    + kcb * 64 + (c64 ^ (kcb & 7)));
        ((int*)B)[chunk * 4 + b4] = pb;
    }

    float d = nl0*ng0 + nl1*ng1 + nl2*ng2 + nl3*ng3;   // exact fp32 diagonal
    for (int m = 1; m < 64; m <<= 1) d += __shfl_xor(d, m, 64);
    if (lane == 0) diag[row] = d;
}

// Kernel 2: fused sim-GEMM + fixed-max sumexp, MX-fp8 32x32x64.
// R6 DMA-prefetch frame (one barrier/tile) + NEW 32-reg-granular software pipeline:
//   chain(accA,c=0); epi(accB_prev); chain(accB,c=1); epi(accA)
// Epilogue registers are independent of the in-flight MFMA chain -> exp2 VALU
// issues into MFMA pipe busy time. Live acc = accA+accB = 64 regs (same as before).
// First epi(accB) is a dummy on zeros (exp2(0)=1) -> lv initialized to -1.0f.
__global__ __launch_bounds__(256, 2) void sim_lse_kernel(
    const unsigned char* __restrict__ A, const unsigned char* __restrict__ B,
    float* __restrict__ lpart)
{
    __shared__ __align__(16) unsigned char bt[2 * BN * DIM];   // 2 x 32 KB double buffer

    int tid  = threadIdx.x;
    int lane = tid & 63;
    int l31  = lane & 31, half = lane >> 5;
    int wave = tid >> 6;
    int seg  = blockIdx.x;
    int rowBase = blockIdx.y * 256 + wave * 64;

    // Preload A fragments: lane(l31,half) holds A[m=l31][k = kk*64 + half*32 + 0..31]
    int8v af[2][4];
#pragma unroll
    for (int s = 0; s < 2; ++s) {
        const unsigned char* ap = A + (size_t)(rowBase + s*32 + l31) * DIM + half * 32;
#pragma unroll
        for (int kk = 0; kk < 4; ++kk) {
            int4 lo = *(const int4*)(ap + kk * 64);
            int4 hi = *(const int4*)(ap + kk * 64 + 16);
            int8v v;
            v[0]=lo.x; v[1]=lo.y; v[2]=lo.z; v[3]=lo.w;
            v[4]=hi.x; v[5]=hi.y; v[6]=hi.z; v[7]=hi.w;
            af[s][kk] = v;
        }
    }

    f32x16 lv[2];
    f32x16 Z;
    f32x16 accA[2], accB[2];
#pragma unroll
    for (int r = 0; r < 16; ++r) {
        lv[0][r] = -1.0f; lv[1][r] = -1.0f;   // compensate the one dummy epilogue
        Z[r] = 0.0f;
        accB[0][r] = 0.0f; accB[1][r] = 0.0f; // dummy-epilogue source
    }

    int T0 = seg * NT;

    auto stage = [&](int T, unsigned bufo) {
        const unsigned char* g = B + (size_t)T * (BN * DIM) + (wave * 512 + lane) * 16;
        unsigned lo = bufo + (unsigned)(wave * 512) * 16;
#pragma unroll
        for (int j = 0; j < 8; ++j) {
            __builtin_amdgcn_global_load_lds(
                (const __attribute__((address_space(1))) unsigned int*)(g + j * 1024),
                (__attribute__((address_space(3))) unsigned int*)&bt[lo + j * 1024],
                16, 0, 0);
        }
    };

    // 8 ds_read_b128 + 8 MFMAs into ac[0..1] for one 64x32 unit (column set c)
    auto chain = [&](f32x16 (&ac)[2], int c, unsigned subo) {
        int8v bfr[4];
#pragma unroll
        for (int kk = 0; kk < 4; ++kk) {
            int col = c * 32 + l31;
            int kcb = kk * 4 + half * 2;
            unsigned p0 = (unsigned)(kcb * 64 + (col ^ (kcb & 7)));
            unsigned p1 = (unsigned)((kcb + 1) * 64 + (col ^ ((kcb + 1) & 7)));
            int4 lo = *(const int4*)&bt[subo + p0 * 16];
            int4 hi = *(const int4*)&bt[subo + p1 * 16];
            int8v v;
            v[0]=lo.x; v[1]=lo.y; v[2]=lo.z; v[3]=lo.w;
            v[4]=hi.x; v[5]=hi.y; v[6]=hi.z; v[7]=hi.w;
            bfr[kk] = v;
        }
        ac[0] = __builtin_amdgcn_mfma_scale_f32_32x32x64_f8f6f4(
            af[0][0], bfr[0], Z, 0, 0, 0, SCALE1, 0, SCALE1);
        ac[1] = __builtin_amdgcn_mfma_scale_f32_32x32x64_f8f6f4(
            af[1][0], bfr[0], Z, 0, 0, 0, SCALE1, 0, SCALE1);
#pragma unroll
        for (int kk = 1; kk < 4; ++kk) {
            ac[0] = __builtin_amdgcn_mfma_scale_f32_32x32x64_f8f6f4(
                af[0][kk], bfr[kk], ac[0], 0, 0, 0, SCALE1, 0, SCALE1);
            ac[1] = __builtin_amdgcn_mfma_scale_f32_32x32x64_f8f6f4(
                af[1][kk], bfr[kk], ac[1], 0, 0, 0, SCALE1, 0, SCALE1);
        }
    };

    // exp2 + accumulate for one finished 64x32 unit
    auto epi = [&](f32x16 (&ac)[2]) {
#pragma unroll
        for (int s = 0; s < 2; ++s) {
            f32x16 e;
#pragma unroll
            for (int r = 0; r < 16; ++r)
                e[r] = __builtin_amdgcn_exp2f(ac[s][r]);
            lv[s] += e;
        }
    };

    stage(T0, 0);

    for (int t = 0; t < NT; ++t) {
        unsigned bufo = (t & 1) ? (unsigned)(BN * DIM) : 0u;
        __syncthreads();   // drains own tile-t DMA (in flight a full tile), syncs waves

        if (t + 1 < NT)
            stage(T0 + t + 1, (t & 1) ? 0u : (unsigned)(BN * DIM));

#pragma unroll
        for (int p = 0; p < 2; ++p) {
            unsigned subo = bufo + (unsigned)p * 16384;
            chain(accA, 0, subo);   // MFMA chain into accA
            epi(accB);              // overlap: epilogue of previous unit (dummy at t=0,p=0)
            chain(accB, 1, subo);   // MFMA chain into accB
            epi(accA);              // overlap: epilogue of accA
        }
    }
    epi(accB);   // final unit

    // Sum across the 32 column-lanes
#pragma unroll
    for (int s = 0; s < 2; ++s)
#pragma unroll
        for (int r = 0; r < 16; ++r) {
            float v = lv[s][r];
            v += __shfl_xor(v, 1, 64);
            v += __shfl_xor(v, 2, 64);
            v += __shfl_xor(v, 4, 64);
            v += __shfl_xor(v, 8, 64);
            v += __shfl_xor(v, 16, 64);
            lv[s][r] = v;
        }
    if (l31 == 0) {
#pragma unroll
        for (int s = 0; s < 2; ++s)
#pragma unroll
            for (int r = 0; r < 16; ++r) {
                int row = rowBase + s*32 + (r & 3) + 8*(r >> 2) + 4*half;
                lpart[(size_t)seg * NROWS + row] = lv[s][r];
            }
    }
}

// Kernel 3: loss_i = -invT*diag_i + ln2*log2(sum_seg l_part), then mean via atomicAdd.
__global__ __launch_bounds__(256) void reduce_kernel(
    const float* __restrict__ lpart, const float* __restrict__ diag,
    float* __restrict__ out)
{
    __shared__ float sm[4];
    int gtid = blockIdx.x * 256 + threadIdx.x;
    float s = 0.0f;
    for (int row = gtid; row < NROWS; row += 32 * 256) {
        float t = 0.0f;
#pragma unroll
        for (int g = 0; g < SEGS; ++g) t += lpart[(size_t)g * NROWS + row];
        s += LN2f * log2f(t) - INVT * diag[row];
    }
    for (int m = 1; m < 64; m <<= 1) s += __shfl_xor(s, m, 64);
    int wave = threadIdx.x >> 6, lane = threadIdx.x & 63;
    if (lane == 0) sm[wave] = s;
    __syncthreads();
    if (threadIdx.x == 0) {
        float tot = sm[0] + sm[1] + sm[2] + sm[3];
        atomicAdd(out, tot * (1.0f / NROWS));
    }
}

extern "C" void kernel_launch(void* const* d_in, const int* in_sizes, int n_in,
                              void* d_out, int out_size, void* d_ws, size_t ws_size,
                              hipStream_t stream) {
    const float* fl = (const float*)d_in[0];
    const float* fg = (const float*)d_in[1];
    float* out = (float*)d_out;

    char* ws = (char*)d_ws;
    unsigned char* A = (unsigned char*)ws;                         // 16384*256 = 4 MB
    unsigned char* B = A + (size_t)NROWS * DIM;                    // 4 MB (swizzled)
    float* diag  = (float*)(ws + 2 * (size_t)NROWS * DIM);         // 64 KB
    float* lpart = diag + NROWS;                                   // SEGS*N*4 = 512 KB

    norm_diag_kernel<<<NROWS / 4, 256, 0, stream>>>(fl, fg, A, B, diag, out);
    sim_lse_kernel<<<dim3(SEGS, NROWS / 256), 256, 0, stream>>>(A, B, lpart);
    reduce_kernel<<<32, 256, 0, stream>>>(lpart, diag, out);
}